// Round 11
// baseline (861.014 us; speedup 1.0000x reference)
//
#include <hip/hip_runtime.h>

typedef __attribute__((ext_vector_type(4))) float f32x4_t;
typedef __attribute__((ext_vector_type(8))) short bf16x8_t;

#define NROWS 16384
#define NCODES 4096
#define DIM 512
#define DELTA 0.005f     // > worst-case |f64 referee - hi-only bf16 pass1| = 0.0040
#define MAXC 16          // candidate cap per row
#define FULL_CAP 4096u   // max full-scan rows (measured fcnt ~1-2)

// ---------------- workspace byte offsets (~41.3 MB; harness provides >=45.6 MB, proven round 4) ----------------
#define WS_A      0u          // 128 tb x 8 st x 16KB (BK=64 stages) -> 16777216
#define WS_B      16777216u   //  32 ct x 8 st x 16KB -> 20971520
#define WS_TOPE   20971520u   // [row 16384][hg 64] float4 -> 37748736
#define WS_COUNTS 37748736u   // 4096 u32 -> 37765120
#define WS_FLAGS  37765120u   // [0]=mask-layout [1]=cand_cnt [2]=full_cnt -> +64
#define WS_IDX    37765184u   // 16384 i32 -> 37830720
#define WS_CANDS  37830720u   // 16384 x 20 i32 -> 39141440
#define WS_FULL   39141440u   // 16384 i32 -> 39206976
#define WS_CPART  39206976u   // 4096 f64 -> 39239744
#define WS_FPART  39239744u   // 4096 x 32 double2 -> 41336896

// output element offsets (flat f32)
#define OUT_ZQ      0
#define OUT_ZQST    8388608
#define OUT_IDX     16777216
#define OUT_VQ      16793600
#define OUT_COMMIT  16793601
#define OUT_PERP    16793602

__device__ __forceinline__ unsigned short f2bf(float x) {
  unsigned u = __builtin_bit_cast(unsigned, x);
  unsigned r = (u + 0x7FFFu + ((u >> 16) & 1u)) >> 16;  // RNE
  return (unsigned short)r;
}
__device__ __forceinline__ unsigned hz(unsigned x) {
  return (x - 0x01010101u) & ~x & 0x80808080u;  // any zero byte
}
// BK=64 stage layout: row r in [0,128) is 128B (8 x 16B units); XOR keeps ds_read banks 2-way (free)
__device__ __forceinline__ unsigned swz64(int r, int u) {
  return (unsigned)(r * 128 + ((u ^ (r & 7)) << 4));
}

// ---------------- prep: norms + bf16-hi convert into swizzled 16KB stage-chunks + zero counts/flags ----------------
__global__ void prep_kernel(const float* __restrict__ z, const float* __restrict__ cb,
                            unsigned char* __restrict__ Aws, unsigned char* __restrict__ Bws,
                            unsigned* __restrict__ counts) {
  if (blockIdx.x < 17) {
    int zi = blockIdx.x * 256 + threadIdx.x;
    if (zi < 4100) counts[zi] = 0;  // counts[4096] + flags[4] contiguous
  }
  const int wv = threadIdx.x >> 6, lane = threadIdx.x & 63;
  const int row = blockIdx.x * 4 + wv;
  if (row >= NROWS + NCODES) return;
  const bool isA = row < NROWS;
  const int lrow = isA ? row : row - NROWS;
  const float* src = (isA ? z : cb) + (size_t)lrow * DIM;
  f32x4_t a = *(const f32x4_t*)(src + lane * 8);
  f32x4_t b = *(const f32x4_t*)(src + lane * 8 + 4);
  double s = 0.0;
#pragma unroll
  for (int e = 0; e < 4; ++e) s += (double)a[e] * a[e] + (double)b[e] * b[e];
#pragma unroll
  for (int off = 1; off < 64; off <<= 1) s += __shfl_xor(s, off);
  const float inv = (float)(1.0 / fmax(sqrt(s), 1e-8));
  union { unsigned short u[8]; uint4 v; } H;
#pragma unroll
  for (int e = 0; e < 4; ++e) {
    H.u[e] = f2bf(a[e] * inv);
    H.u[4 + e] = f2bf(b[e] * inv);
  }
  const int tb = lrow >> 7, rr = lrow & 127;
  const int st = lane >> 3, u = lane & 7;  // stage = 64 cols, unit = 8 cols
  unsigned char* chunk = (isA ? Aws : Bws) + ((size_t)tb * 8 + st) * 16384;
  *(uint4*)(chunk + swz64(rr, u)) = H.v;
}

// ---------------- pass-1 GEMM: BK=64 single-buffer + in-register cross-lane top-2 epilogue ----------------
__global__ __launch_bounds__(256, 4) void gemm_p1_kernel(
    const unsigned char* __restrict__ Aws, const unsigned char* __restrict__ Bws,
    float4* __restrict__ topE) {
  __align__(16) __shared__ unsigned char smem[32768];  // staging only (A 16K | B 16K); no slog

  const int tid = threadIdx.x;
  const int bid = blockIdx.x;
  const int xcd = bid & 7, q = bid >> 3;
  const int rb = xcd * 16 + (q >> 3), cg = q & 7;  // XCD-aware: 8 cg-blocks of one rb share an XCD L2
  const int wave = tid >> 6, lane = tid & 63;
  const int wr = wave >> 1, wc = wave & 1;
  const int kg = lane >> 4, lr = lane & 15;

  const unsigned char* Ach = Aws + (size_t)rb * 8 * 16384;

  auto issue_stage = [&](const unsigned char* Asrc, const unsigned char* Bsrc) {
#pragma unroll
    for (int i = 0; i < 8; ++i) {
      const int j = wave * 8 + i;  // 32 x 1KB units: A 0-15 -> lds 0-16K, B 16-31 -> lds 16-32K
      const unsigned char* sp = (j < 16) ? (Asrc + (size_t)j * 1024 + lane * 16)
                                         : (Bsrc + (size_t)(j - 16) * 1024 + lane * 16);
      __builtin_amdgcn_global_load_lds(
          (const __attribute__((address_space(1))) void*)sp,
          (__attribute__((address_space(3))) void*)(smem + j * 1024), 16, 0, 0);
    }
  };

  for (int ct = 0; ct < 4; ++ct) {
    const int ctile = cg * 4 + ct;
    const int code0 = ctile * 128;
    const unsigned char* Bch = Bws + (size_t)ctile * 8 * 16384;

    f32x4_t acc[4][4];
#pragma unroll
    for (int m = 0; m < 4; ++m)
#pragma unroll
      for (int n = 0; n < 4; ++n) acc[m][n] = (f32x4_t){0.f, 0.f, 0.f, 0.f};

    for (int st = 0; st < 8; ++st) {
      if (!(st == 0 && ct > 0))  // ct>0 stage-0 was pre-issued before previous epilogue
        issue_stage(Ach + (size_t)st * 16384, Bch + (size_t)st * 16384);
      __syncthreads();  // compiler drains vmcnt before barrier (m97 pattern)

#pragma unroll
      for (int kk = 0; kk < 2; ++kk) {  // two 32-col halves; frags scoped to stay <=128 VGPR
        bf16x8_t ah[4], bh[4];
        const int u = kk * 4 + kg;
#pragma unroll
        for (int m = 0; m < 4; ++m) {
          const int r = wr * 64 + m * 16 + lr;
          ah[m] = *(const bf16x8_t*)(smem + swz64(r, u));
        }
#pragma unroll
        for (int n = 0; n < 4; ++n) {
          const int r = wc * 64 + n * 16 + lr;
          bh[n] = *(const bf16x8_t*)(smem + 16384 + swz64(r, u));
        }
#pragma unroll
        for (int m = 0; m < 4; ++m)
#pragma unroll
          for (int n = 0; n < 4; ++n)
            acc[m][n] = __builtin_amdgcn_mfma_f32_16x16x32_bf16(ah[m], bh[n], acc[m][n], 0, 0, 0);
      }
      __syncthreads();  // reads done before next stage overwrites
    }

    // pre-issue next ct's first stage: its HBM/L2 latency hides under the butterfly below
    if (ct < 3)
      issue_stage(Ach, Bws + (size_t)(ctile + 1) * 8 * 16384);

    // epilogue: exact top-2 per (row, 64-code half) fully in-register (no LDS, no barriers)
#pragma unroll
    for (int m = 0; m < 4; ++m) {
#pragma unroll
      for (int j = 0; j < 4; ++j) {
        float v1 = -3e38f, v2 = -3e38f; int i1 = 0, i2 = 0;
#pragma unroll
        for (int n = 0; n < 4; ++n) {  // ascending code order; strict > keeps smallest index on ties
          float v = acc[m][n][j];
          int gc = code0 + wc * 64 + n * 16 + lr;
          if (v > v1) { v2 = v1; i2 = i1; v1 = v; i1 = gc; }
          else if (v > v2) { v2 = v; i2 = gc; }
        }
#pragma unroll
        for (int mask = 1; mask <= 8; mask <<= 1) {  // butterfly over lr: merge sorted-2 lists
          float ov1 = __shfl_xor(v1, mask); int oi1 = __shfl_xor(i1, mask);
          float ov2 = __shfl_xor(v2, mask); int oi2 = __shfl_xor(i2, mask);
          bool of = (ov1 > v1) || (ov1 == v1 && oi1 < i1);
          float w1 = of ? ov1 : v1;  int k1 = of ? oi1 : i1;
          float lv = of ? v1 : ov1;  int li = of ? i1 : oi1;
          float sv = of ? ov2 : v2;  int si = of ? oi2 : i2;
          bool lw = (lv > sv) || (lv == sv && li < si);
          v1 = w1; i1 = k1;
          v2 = lw ? lv : sv; i2 = lw ? li : si;
        }
        if (lr == m * 4 + j) {  // one lane per (m,j): every lane writes exactly one float4
          const int row = rb * 128 + wr * 64 + m * 16 + kg * 4 + j;
          topE[(size_t)row * 64 + ctile * 2 + wc] =
              make_float4(v1, __builtin_bit_cast(float, i1), v2, __builtin_bit_cast(float, i2));
        }
      }
    }
  }
}

// ---------------- resolve: mask probe + stream 64 half-group top-2s, classify rows ----------------
__global__ void resolve_kernel(const uint4* __restrict__ mk, const float4* __restrict__ topE,
                               int* __restrict__ idxf, int* __restrict__ cands,
                               int* __restrict__ full, unsigned* __restrict__ flags) {
  if (blockIdx.x == 0) {
    unsigned f = 0;
    for (int i = threadIdx.x; i < 1024; i += 256) {
      uint4 v = mk[i];
      f |= hz(v.x) | hz(v.y) | hz(v.z) | hz(v.w);
    }
    if (f) atomicOr(&flags[0], 1u);  // zero byte found -> int32 mask layout
  }
  const int row = blockIdx.x * 256 + threadIdx.x;
  if (row >= NROWS) return;
  const float4* e = topE + (size_t)row * 64;
  float V1 = -3e38f; int I1 = 0;
  for (int h = 0; h < 64; ++h) {  // hg ascending = code ascending; strict > = np smallest-index ties
    float4 qv = e[h];
    if (qv.x > V1) { V1 = qv.x; I1 = __builtin_bit_cast(int, qv.y); }
  }
  const float T = V1 - 2.0f * DELTA;
  bool fullscan = false;
  int cnt = 0; int cid[MAXC];
  for (int h = 0; h < 64; ++h) {
    float4 qv = e[h];
    if (qv.x >= T) { if (cnt < MAXC) cid[cnt] = __builtin_bit_cast(int, qv.y); ++cnt; }
    if (qv.z >= T) fullscan = true;  // 3rd candidate may hide below half-group's top-2
  }
  if (cnt > MAXC) fullscan = true;
  idxf[row] = I1;  // provably correct when cnt==1
  if (fullscan) {
    unsigned s = atomicAdd(&flags[2], 1u);
    if (s < FULL_CAP) full[s] = row;
  } else if (cnt >= 2) {
    unsigned s = atomicAdd(&flags[1], 1u);
    int* o = cands + (size_t)s * 20;
    o[0] = row; o[1] = cnt;
#pragma unroll
    for (int c2 = 0; c2 < MAXC; ++c2) o[2 + c2] = (c2 < cnt) ? cid[c2] : 0;
  }
}

// ---------------- f64 candidate rescore: one wave per row ----------------
__global__ void rescore_cand_kernel(const float* __restrict__ z, const float* __restrict__ cb,
                                    const int* __restrict__ cands, const unsigned* __restrict__ flags,
                                    int* __restrict__ idxf) {
  const int lane = threadIdx.x & 63;
  const int gw = (blockIdx.x * 256 + threadIdx.x) >> 6;
  const unsigned n = flags[1];
  for (unsigned it = gw; it < n; it += 512) {
    const int* en = cands + (size_t)it * 20;
    const int row = en[0], cnt = en[1];
    const float* zr = z + (size_t)row * DIM + lane * 8;
    double zv[8];
#pragma unroll
    for (int j = 0; j < 8; ++j) zv[j] = (double)zr[j];
    double bs = -1e300; int bi = 1 << 30;
    for (int c = 0; c < cnt; ++c) {
      const int k = en[2 + c];
      const float* ck = cb + (size_t)k * DIM + lane * 8;
      double da = 0, nb = 0;
#pragma unroll
      for (int j = 0; j < 8; ++j) { double cv = ck[j]; da += zv[j] * cv; nb += cv * cv; }
#pragma unroll
      for (int off = 1; off < 64; off <<= 1) {
        da += __shfl_xor(da, off); nb += __shfl_xor(nb, off);
      }
      double sc = da / sqrt(nb);  // z-norm omitted: row-constant scale, argmax-invariant
      if (sc > bs || (sc == bs && k < bi)) { bs = sc; bi = k; }
    }
    if (lane == 0) idxf[row] = bi;
  }
}

// ---------------- f64 full-row referee stage 1: (row, 128-code chunk) work units ----------------
__global__ void rescore_full_part(const float* __restrict__ z, const float* __restrict__ cb,
                                  const int* __restrict__ full, const unsigned* __restrict__ flags,
                                  double2* __restrict__ fpart) {
  __shared__ float zrow[DIM];
  __shared__ double sv[128];
  __shared__ int si[128];
  const int t = threadIdx.x;
  unsigned n = flags[2];
  if (n > FULL_CAP) n = FULL_CAP;
  for (unsigned u = blockIdx.x; u < n * 32; u += gridDim.x) {
    const unsigned it = u >> 5, chunk = u & 31;
    const int row = full[it];
    __syncthreads();  // protect zrow from previous iteration's readers
    for (int j = t; j < DIM; j += 256) zrow[j] = z[(size_t)row * DIM + j];
    __syncthreads();
    const int k = (int)chunk * 128 + (t >> 1);
    const int half = t & 1;
    const float* ck = cb + (size_t)k * DIM + half * 256;
    const float* zp = zrow + half * 256;
    double d = 0, nn = 0;
    for (int j = 0; j < 256; j += 4) {
      f32x4_t cv = *(const f32x4_t*)(ck + j);
      f32x4_t zv = *(const f32x4_t*)(zp + j);
#pragma unroll
      for (int e = 0; e < 4; ++e) {
        const double c = (double)cv[e];
        d += (double)zv[e] * c; nn += c * c;
      }
    }
    d += __shfl_xor(d, 1); nn += __shfl_xor(nn, 1);
    if (half == 0) { sv[t >> 1] = d / sqrt(nn); si[t >> 1] = k; }
    __syncthreads();
    for (int off = 64; off; off >>= 1) {
      if (t < off) {
        if (sv[t + off] > sv[t] || (sv[t + off] == sv[t] && si[t + off] < si[t])) {
          sv[t] = sv[t + off]; si[t] = si[t + off];
        }
      }
      __syncthreads();
    }
    if (t == 0) fpart[u] = make_double2(sv[0], (double)si[0]);
  }
}

// ---------------- f64 full-row referee stage 2: merge 32 chunk-bests per row ----------------
__global__ void rescore_full_merge(const double2* __restrict__ fpart, const int* __restrict__ full,
                                   const unsigned* __restrict__ flags, int* __restrict__ idxf) {
  const int wv = threadIdx.x >> 6, lane = threadIdx.x & 63;
  unsigned n = flags[2];
  if (n > FULL_CAP) n = FULL_CAP;
  for (unsigned it = blockIdx.x * 4 + wv; it < n; it += gridDim.x * 4) {
    double bs = -1e300; int bi = 1 << 30;
    if (lane < 32) {
      double2 e = fpart[(size_t)it * 32 + lane];
      bs = e.x; bi = (int)e.y;
    }
#pragma unroll
    for (int off = 16; off; off >>= 1) {
      double os = __shfl_down(bs, off);
      int oi = __shfl_down(bi, off);
      if (os > bs || (os == bs && oi < bi)) { bs = os; bi = oi; }
    }
    if (lane == 0) idxf[full[it]] = bi;
  }
}

// ---------------- gather + straight-through + partial losses ----------------
__global__ void outputs_kernel(const float* __restrict__ z, const float* __restrict__ cb,
                               const unsigned char* __restrict__ mask8, const int* __restrict__ mask32,
                               const unsigned* __restrict__ flags, const int* __restrict__ idxf,
                               float* __restrict__ out, unsigned* __restrict__ counts,
                               double* __restrict__ cpart) {
  __shared__ double wsum[4];
  const int wv = threadIdx.x >> 6, lane = threadIdx.x & 63;
  const int row = blockIdx.x * 4 + wv;
  int idx = idxf[row];
  idx = (idx < 0) ? 0 : ((idx > NCODES - 1) ? NCODES - 1 : idx);  // defensive clamp
  const int mi = flags[0] ? (mask32[row] != 0) : (mask8[row] != 0);
  const float mf = mi ? 1.0f : 0.0f;
  const float* zr = z + (size_t)row * DIM;
  const float* cr = cb + (size_t)idx * DIM;
  double cs = 0.0;
#pragma unroll
  for (int h = 0; h < 2; ++h) {
    const int j = h * 256 + lane * 4;
    f32x4_t c  = *(const f32x4_t*)(cr + j);
    f32x4_t ze = *(const f32x4_t*)(zr + j);
    f32x4_t zq, zs;
#pragma unroll
    for (int e = 0; e < 4; ++e) {
      float qv = c[e] * mf;
      float d = qv - ze[e];
      zq[e] = qv;
      zs[e] = ze[e] + d;
      cs += (double)(d * d) * mf;
    }
    *(f32x4_t*)(out + OUT_ZQ   + (size_t)row * DIM + j) = zq;
    *(f32x4_t*)(out + OUT_ZQST + (size_t)row * DIM + j) = zs;
  }
#pragma unroll
  for (int off = 32; off; off >>= 1) cs += __shfl_down(cs, off);
  if (lane == 0) {
    wsum[wv] = cs;
    out[OUT_IDX + row] = (float)idx;
    if (mi) atomicAdd(&counts[idx], 1u);
  }
  __syncthreads();
  if (threadIdx.x == 0) cpart[blockIdx.x] = wsum[0] + wsum[1] + wsum[2] + wsum[3];
}

// ---------------- scalars ----------------
__global__ void finalize_kernel(const double* __restrict__ cpart, const unsigned* __restrict__ counts,
                                float* __restrict__ out) {
  __shared__ double sd[256];
  const int t = threadIdx.x;
  double s = 0;
  for (int i = t; i < 4096; i += 256) s += cpart[i];
  sd[t] = s; __syncthreads();
  for (int off = 128; off; off >>= 1) { if (t < off) sd[t] += sd[t + off]; __syncthreads(); }
  const double commit_sum = sd[0];
  __syncthreads();
  double c = 0;
  for (int i = t; i < 4096; i += 256) c += (double)counts[i];
  sd[t] = c; __syncthreads();
  for (int off = 128; off; off >>= 1) { if (t < off) sd[t] += sd[t + off]; __syncthreads(); }
  const double totc = sd[0];
  __syncthreads();
  const double denom = totc + 1e-5;
  double ent = 0;
  for (int i = t; i < 4096; i += 256) {
    double p = (double)counts[i] / denom;
    ent -= p * log(p + 1e-5);
  }
  sd[t] = ent; __syncthreads();
  for (int off = 128; off; off >>= 1) { if (t < off) sd[t] += sd[t + off]; __syncthreads(); }
  if (t == 0) {
    const double valid = fmax(totc, 1.0);
    const double commitment = commit_sum / valid;
    out[OUT_VQ]     = (float)(0.25 * commitment);
    out[OUT_COMMIT] = (float)commitment;
    out[OUT_PERP]   = (float)exp(sd[0]);
  }
}

extern "C" void kernel_launch(void* const* d_in, const int* in_sizes, int n_in,
                              void* d_out, int out_size, void* d_ws, size_t ws_size,
                              hipStream_t stream) {
  const float* z  = (const float*)d_in[0];
  const void*  mk = d_in[1];
  const float* cb = (const float*)d_in[2];
  float* out = (float*)d_out;
  char* ws = (char*)d_ws;

  unsigned char* Aws    = (unsigned char*)(ws + WS_A);
  unsigned char* Bws    = (unsigned char*)(ws + WS_B);
  float4*        topE   = (float4*)(ws + WS_TOPE);
  unsigned*      counts = (unsigned*)(ws + WS_COUNTS);
  unsigned*      flags  = (unsigned*)(ws + WS_FLAGS);
  int*           idxf   = (int*)(ws + WS_IDX);
  int*           cands  = (int*)(ws + WS_CANDS);
  int*           full   = (int*)(ws + WS_FULL);
  double*        cpart  = (double*)(ws + WS_CPART);
  double2*       fpart  = (double2*)(ws + WS_FPART);

  prep_kernel<<<(NROWS + NCODES) / 4, 256, 0, stream>>>(z, cb, Aws, Bws, counts);
  gemm_p1_kernel<<<1024, 256, 0, stream>>>(Aws, Bws, topE);
  resolve_kernel<<<NROWS / 256, 256, 0, stream>>>((const uint4*)mk, topE, idxf, cands, full, flags);
  rescore_cand_kernel<<<128, 256, 0, stream>>>(z, cb, cands, flags, idxf);
  rescore_full_part<<<1024, 256, 0, stream>>>(z, cb, full, flags, fpart);
  rescore_full_merge<<<32, 256, 0, stream>>>(fpart, full, flags, idxf);
  outputs_kernel<<<NROWS / 4, 256, 0, stream>>>(z, cb, (const unsigned char*)mk, (const int*)mk,
                                                flags, idxf, out, counts, cpart);
  finalize_kernel<<<1, 256, 0, stream>>>(cpart, counts, out);
}

// Round 13
// 347.901 us; speedup vs baseline: 2.4749x; 2.4749x over previous
//
#include <hip/hip_runtime.h>

typedef __attribute__((ext_vector_type(4))) float f32x4_t;
typedef __attribute__((ext_vector_type(8))) short bf16x8_t;

#define NROWS 16384
#define NCODES 4096
#define DIM 512
#define DELTA 0.005f     // > worst-case |f64 referee - hi-only bf16 pass1| = 0.0040
#define MAXC 16          // explicit candidate cap per row (overflow -> group bit)

// ---------------- workspace byte offsets (~41 MB; harness provides >=45.6 MB, proven round 4) ----------------
#define WS_A      0u          // 128 tb x 8 st x 16KB (BK=64 stages) -> 16777216
#define WS_B      16777216u   //  32 ct x 8 st x 16KB -> 20971520
#define WS_TOPE   20971520u   // [row 16384][hg 64] float4 -> 37748736
#define WS_COUNTS 37748736u   // 4096 u32 -> 37765120
#define WS_FLAGS  37765120u   // [0]=mask-layout [1]=item_cnt -> +64
#define WS_IDX    37765184u   // 16384 i32 -> 37830720
#define WS_ITEMS  37830720u   // 16384 x 20 i32 {row,cnt,maskLo,maskHi,cid[16]} -> 39141440
#define WS_CPART  39206976u   // 4096 f64 -> 39239744

// output element offsets (flat f32)
#define OUT_ZQ      0
#define OUT_ZQST    8388608
#define OUT_IDX     16777216
#define OUT_VQ      16793600
#define OUT_COMMIT  16793601
#define OUT_PERP    16793602

__device__ __forceinline__ unsigned short f2bf(float x) {
  unsigned u = __builtin_bit_cast(unsigned, x);
  unsigned r = (u + 0x7FFFu + ((u >> 16) & 1u)) >> 16;  // RNE
  return (unsigned short)r;
}
__device__ __forceinline__ unsigned hz(unsigned x) {
  return (x - 0x01010101u) & ~x & 0x80808080u;  // any zero byte
}
// BK=64 stage layout: row r in [0,128) is 128B (8 x 16B units); XOR keeps ds_read banks 2-way (free)
__device__ __forceinline__ unsigned swz64(int r, int u) {
  return (unsigned)(r * 128 + ((u ^ (r & 7)) << 4));
}

// ---------------- prep: norms + bf16-hi convert into swizzled 16KB stage-chunks + zero counts/flags ----------------
__global__ void prep_kernel(const float* __restrict__ z, const float* __restrict__ cb,
                            unsigned char* __restrict__ Aws, unsigned char* __restrict__ Bws,
                            unsigned* __restrict__ counts) {
  if (blockIdx.x < 17) {
    int zi = blockIdx.x * 256 + threadIdx.x;
    if (zi < 4100) counts[zi] = 0;  // counts[4096] + flags[4] contiguous
  }
  const int wv = threadIdx.x >> 6, lane = threadIdx.x & 63;
  const int row = blockIdx.x * 4 + wv;
  if (row >= NROWS + NCODES) return;
  const bool isA = row < NROWS;
  const int lrow = isA ? row : row - NROWS;
  const float* src = (isA ? z : cb) + (size_t)lrow * DIM;
  f32x4_t a = *(const f32x4_t*)(src + lane * 8);
  f32x4_t b = *(const f32x4_t*)(src + lane * 8 + 4);
  double s = 0.0;
#pragma unroll
  for (int e = 0; e < 4; ++e) s += (double)a[e] * a[e] + (double)b[e] * b[e];
#pragma unroll
  for (int off = 1; off < 64; off <<= 1) s += __shfl_xor(s, off);
  const float inv = (float)(1.0 / fmax(sqrt(s), 1e-8));
  union { unsigned short u[8]; uint4 v; } H;
#pragma unroll
  for (int e = 0; e < 4; ++e) {
    H.u[e] = f2bf(a[e] * inv);
    H.u[4 + e] = f2bf(b[e] * inv);
  }
  const int tb = lrow >> 7, rr = lrow & 127;
  const int st = lane >> 3, u = lane & 7;  // stage = 64 cols, unit = 8 cols
  unsigned char* chunk = (isA ? Aws : Bws) + ((size_t)tb * 8 + st) * 16384;
  *(uint4*)(chunk + swz64(rr, u)) = H.v;
}

// ---------------- pass-1 GEMM: BK=64 single-buffer + in-register cross-lane top-2 epilogue ----------------
__global__ __launch_bounds__(256, 4) void gemm_p1_kernel(
    const unsigned char* __restrict__ Aws, const unsigned char* __restrict__ Bws,
    float4* __restrict__ topE) {
  __align__(16) __shared__ unsigned char smem[32768];  // staging only (A 16K | B 16K)

  const int tid = threadIdx.x;
  const int bid = blockIdx.x;
  const int xcd = bid & 7, q = bid >> 3;
  const int rb = xcd * 16 + (q >> 3), cg = q & 7;  // XCD-aware: 8 cg-blocks of one rb share an XCD L2
  const int wave = tid >> 6, lane = tid & 63;
  const int wr = wave >> 1, wc = wave & 1;
  const int kg = lane >> 4, lr = lane & 15;

  const unsigned char* Ach = Aws + (size_t)rb * 8 * 16384;

  auto issue_stage = [&](const unsigned char* Asrc, const unsigned char* Bsrc) {
#pragma unroll
    for (int i = 0; i < 8; ++i) {
      const int j = wave * 8 + i;  // 32 x 1KB units: A 0-15 -> lds 0-16K, B 16-31 -> lds 16-32K
      const unsigned char* sp = (j < 16) ? (Asrc + (size_t)j * 1024 + lane * 16)
                                         : (Bsrc + (size_t)(j - 16) * 1024 + lane * 16);
      __builtin_amdgcn_global_load_lds(
          (const __attribute__((address_space(1))) void*)sp,
          (__attribute__((address_space(3))) void*)(smem + j * 1024), 16, 0, 0);
    }
  };

  for (int ct = 0; ct < 4; ++ct) {
    const int ctile = cg * 4 + ct;
    const int code0 = ctile * 128;
    const unsigned char* Bch = Bws + (size_t)ctile * 8 * 16384;

    f32x4_t acc[4][4];
#pragma unroll
    for (int m = 0; m < 4; ++m)
#pragma unroll
      for (int n = 0; n < 4; ++n) acc[m][n] = (f32x4_t){0.f, 0.f, 0.f, 0.f};

    for (int st = 0; st < 8; ++st) {
      if (!(st == 0 && ct > 0))  // ct>0 stage-0 was pre-issued before previous epilogue
        issue_stage(Ach + (size_t)st * 16384, Bch + (size_t)st * 16384);
      __syncthreads();  // compiler drains vmcnt before barrier (m97 pattern)

#pragma unroll
      for (int kk = 0; kk < 2; ++kk) {  // two 32-col halves; frags scoped to stay <=128 VGPR
        bf16x8_t ah[4], bh[4];
        const int u = kk * 4 + kg;
#pragma unroll
        for (int m = 0; m < 4; ++m) {
          const int r = wr * 64 + m * 16 + lr;
          ah[m] = *(const bf16x8_t*)(smem + swz64(r, u));
        }
#pragma unroll
        for (int n = 0; n < 4; ++n) {
          const int r = wc * 64 + n * 16 + lr;
          bh[n] = *(const bf16x8_t*)(smem + 16384 + swz64(r, u));
        }
#pragma unroll
        for (int m = 0; m < 4; ++m)
#pragma unroll
          for (int n = 0; n < 4; ++n)
            acc[m][n] = __builtin_amdgcn_mfma_f32_16x16x32_bf16(ah[m], bh[n], acc[m][n], 0, 0, 0);
      }
      __syncthreads();  // reads done before next stage overwrites
    }

    // pre-issue next ct's first stage: its HBM/L2 latency hides under the butterfly below
    if (ct < 3)
      issue_stage(Ach, Bws + (size_t)(ctile + 1) * 8 * 16384);

    // epilogue: exact top-2 per (row, 64-code half) fully in-register (no LDS, no barriers)
#pragma unroll
    for (int m = 0; m < 4; ++m) {
#pragma unroll
      for (int j = 0; j < 4; ++j) {
        float v1 = -3e38f, v2 = -3e38f; int i1 = 0, i2 = 0;
#pragma unroll
        for (int n = 0; n < 4; ++n) {  // ascending code order; strict > keeps smallest index on ties
          float v = acc[m][n][j];
          int gc = code0 + wc * 64 + n * 16 + lr;
          if (v > v1) { v2 = v1; i2 = i1; v1 = v; i1 = gc; }
          else if (v > v2) { v2 = v; i2 = gc; }
        }
#pragma unroll
        for (int mask = 1; mask <= 8; mask <<= 1) {  // butterfly over lr: merge sorted-2 lists
          float ov1 = __shfl_xor(v1, mask); int oi1 = __shfl_xor(i1, mask);
          float ov2 = __shfl_xor(v2, mask); int oi2 = __shfl_xor(i2, mask);
          bool of = (ov1 > v1) || (ov1 == v1 && oi1 < i1);
          float w1 = of ? ov1 : v1;  int k1 = of ? oi1 : i1;
          float lv = of ? v1 : ov1;  int li = of ? i1 : oi1;
          float sv = of ? ov2 : v2;  int si = of ? oi2 : i2;
          bool lw = (lv > sv) || (lv == sv && li < si);
          v1 = w1; i1 = k1;
          v2 = lw ? lv : sv; i2 = lw ? li : si;
        }
        if (lr == m * 4 + j) {  // one lane per (m,j): every lane writes exactly one float4
          const int row = rb * 128 + wr * 64 + m * 16 + kg * 4 + j;
          topE[(size_t)row * 64 + ctile * 2 + wc] =
              make_float4(v1, __builtin_bit_cast(float, i1), v2, __builtin_bit_cast(float, i2));
        }
      }
    }
  }
}

// ---------------- resolve: mask probe + classify rows into {direct, groupscan item} ----------------
__global__ void resolve_kernel(const uint4* __restrict__ mk, const float4* __restrict__ topE,
                               int* __restrict__ idxf, int* __restrict__ items,
                               unsigned* __restrict__ flags) {
  if (blockIdx.x == 0) {
    unsigned f = 0;
    for (int i = threadIdx.x; i < 1024; i += 256) {
      uint4 v = mk[i];
      f |= hz(v.x) | hz(v.y) | hz(v.z) | hz(v.w);
    }
    if (f) atomicOr(&flags[0], 1u);  // zero byte found -> int32 mask layout
  }
  const int row = blockIdx.x * 256 + threadIdx.x;
  if (row >= NROWS) return;
  const float4* e = topE + (size_t)row * 64;
  float V1 = -3e38f; int I1 = 0;
  for (int h = 0; h < 64; ++h) {  // hg ascending = code ascending; strict > = np smallest-index ties
    float4 qv = e[h];
    if (qv.x > V1) { V1 = qv.x; I1 = __builtin_bit_cast(int, qv.y); }
  }
  const float T = V1 - 2.0f * DELTA;
  unsigned long long smask = 0ull;  // suspect half-groups: their top-2 may hide a 3rd candidate
  int cnt = 0; int cid[MAXC];
  for (int h = 0; h < 64; ++h) {
    float4 qv = e[h];
    if (qv.x >= T) {
      if (cnt < MAXC) cid[cnt++] = __builtin_bit_cast(int, qv.y);
      else smask |= 1ull << h;           // overflow candidate -> scan its whole group
    }
    if (qv.z >= T) smask |= 1ull << h;   // group 2nd-best in window -> scan whole group
  }
  idxf[row] = I1;  // exact when cnt==1 && smask==0 (only one code can reach V1 within error bound)
  if (cnt >= 2 || smask != 0ull) {
    unsigned s = atomicAdd(&flags[1], 1u);
    if (s < NROWS) {
      int* o = items + (size_t)s * 20;
      o[0] = row; o[1] = cnt;
      o[2] = (int)(unsigned)(smask & 0xFFFFFFFFull);
      o[3] = (int)(unsigned)(smask >> 32);
#pragma unroll
      for (int c2 = 0; c2 < MAXC; ++c2) o[4 + c2] = (c2 < cnt) ? cid[c2] : 0;
    }
  }
}

// ---------------- f64 referee: one wave per item; explicit candidates + suspect groups only ----------------
__global__ void groupscan_kernel(const float* __restrict__ z, const float* __restrict__ cb,
                                 const int* __restrict__ items, const unsigned* __restrict__ flags,
                                 int* __restrict__ idxf) {
  const int lane = threadIdx.x & 63;
  const int gw = (blockIdx.x * 256 + threadIdx.x) >> 6;
  const int nwaves = gridDim.x * 4;
  unsigned n = flags[1];
  if (n > (unsigned)NROWS) n = NROWS;
  for (unsigned it = gw; it < n; it += nwaves) {
    const int* en = items + (size_t)it * 20;
    const int row = en[0], cnt = en[1];
    unsigned long long smask = ((unsigned long long)(unsigned)en[3] << 32) | (unsigned)en[2];
    const float* zr = z + (size_t)row * DIM + lane * 8;
    double zv[8];
#pragma unroll
    for (int j = 0; j < 8; ++j) zv[j] = (double)zr[j];
    double bs = -1e300; int bi = 1 << 30;
    auto score2 = [&](int k0, int k1) {  // two codes with ILP; k1<0 -> single
      const float* c0 = cb + (size_t)k0 * DIM + lane * 8;
      const float* c1 = cb + (size_t)((k1 < 0) ? k0 : k1) * DIM + lane * 8;
      double d0 = 0, n0 = 0, d1 = 0, n1 = 0;
#pragma unroll
      for (int j = 0; j < 8; ++j) {
        double a = c0[j]; d0 += zv[j] * a; n0 += a * a;
        double b = c1[j]; d1 += zv[j] * b; n1 += b * b;
      }
#pragma unroll
      for (int off = 1; off < 64; off <<= 1) {
        d0 += __shfl_xor(d0, off); n0 += __shfl_xor(n0, off);
        d1 += __shfl_xor(d1, off); n1 += __shfl_xor(n1, off);
      }
      double s0 = d0 / sqrt(n0);
      if (s0 > bs || (s0 == bs && k0 < bi)) { bs = s0; bi = k0; }
      if (k1 >= 0) {
        double s1 = d1 / sqrt(n1);
        if (s1 > bs || (s1 == bs && k1 < bi)) { bs = s1; bi = k1; }
      }
    };
    for (int c = 0; c + 1 < cnt; c += 2) score2(en[4 + c], en[5 + c]);
    if (cnt & 1) score2(en[4 + cnt - 1], -1);
    unsigned long long m = smask;
    while (m) {
      const int g = __builtin_ctzll(m);
      m &= m - 1;
      const int base = g * 64;
      for (int k = 0; k < 64; k += 2) score2(base + k, base + k + 1);
    }
    if (lane == 0) idxf[row] = bi;
  }
}

// ---------------- gather + straight-through + partial losses ----------------
__global__ void outputs_kernel(const float* __restrict__ z, const float* __restrict__ cb,
                               const unsigned char* __restrict__ mask8, const int* __restrict__ mask32,
                               const unsigned* __restrict__ flags, const int* __restrict__ idxf,
                               float* __restrict__ out, unsigned* __restrict__ counts,
                               double* __restrict__ cpart) {
  __shared__ double wsum[4];
  const int wv = threadIdx.x >> 6, lane = threadIdx.x & 63;
  const int row = blockIdx.x * 4 + wv;
  int idx = idxf[row];
  idx = (idx < 0) ? 0 : ((idx > NCODES - 1) ? NCODES - 1 : idx);  // defensive clamp
  const int mi = flags[0] ? (mask32[row] != 0) : (mask8[row] != 0);
  const float mf = mi ? 1.0f : 0.0f;
  const float* zr = z + (size_t)row * DIM;
  const float* cr = cb + (size_t)idx * DIM;
  double cs = 0.0;
#pragma unroll
  for (int h = 0; h < 2; ++h) {
    const int j = h * 256 + lane * 4;
    f32x4_t c  = *(const f32x4_t*)(cr + j);
    f32x4_t ze = *(const f32x4_t*)(zr + j);
    f32x4_t zq, zs;
#pragma unroll
    for (int e = 0; e < 4; ++e) {
      float qv = c[e] * mf;
      float d = qv - ze[e];
      zq[e] = qv;
      zs[e] = ze[e] + d;
      cs += (double)(d * d) * mf;
    }
    *(f32x4_t*)(out + OUT_ZQ   + (size_t)row * DIM + j) = zq;
    *(f32x4_t*)(out + OUT_ZQST + (size_t)row * DIM + j) = zs;
  }
#pragma unroll
  for (int off = 32; off; off >>= 1) cs += __shfl_down(cs, off);
  if (lane == 0) {
    wsum[wv] = cs;
    out[OUT_IDX + row] = (float)idx;
    if (mi) atomicAdd(&counts[idx], 1u);
  }
  __syncthreads();
  if (threadIdx.x == 0) cpart[blockIdx.x] = wsum[0] + wsum[1] + wsum[2] + wsum[3];
}

// ---------------- scalars ----------------
__global__ void finalize_kernel(const double* __restrict__ cpart, const unsigned* __restrict__ counts,
                                float* __restrict__ out) {
  __shared__ double sd[256];
  const int t = threadIdx.x;
  double s = 0;
  for (int i = t; i < 4096; i += 256) s += cpart[i];
  sd[t] = s; __syncthreads();
  for (int off = 128; off; off >>= 1) { if (t < off) sd[t] += sd[t + off]; __syncthreads(); }
  const double commit_sum = sd[0];
  __syncthreads();
  double c = 0;
  for (int i = t; i < 4096; i += 256) c += (double)counts[i];
  sd[t] = c; __syncthreads();
  for (int off = 128; off; off >>= 1) { if (t < off) sd[t] += sd[t + off]; __syncthreads(); }
  const double totc = sd[0];
  __syncthreads();
  const double denom = totc + 1e-5;
  double ent = 0;
  for (int i = t; i < 4096; i += 256) {
    double p = (double)counts[i] / denom;
    ent -= p * log(p + 1e-5);
  }
  sd[t] = ent; __syncthreads();
  for (int off = 128; off; off >>= 1) { if (t < off) sd[t] += sd[t + off]; __syncthreads(); }
  if (t == 0) {
    const double valid = fmax(totc, 1.0);
    const double commitment = commit_sum / valid;
    out[OUT_VQ]     = (float)(0.25 * commitment);
    out[OUT_COMMIT] = (float)commitment;
    out[OUT_PERP]   = (float)exp(sd[0]);
  }
}

extern "C" void kernel_launch(void* const* d_in, const int* in_sizes, int n_in,
                              void* d_out, int out_size, void* d_ws, size_t ws_size,
                              hipStream_t stream) {
  const float* z  = (const float*)d_in[0];
  const void*  mk = d_in[1];
  const float* cb = (const float*)d_in[2];
  float* out = (float*)d_out;
  char* ws = (char*)d_ws;

  unsigned char* Aws    = (unsigned char*)(ws + WS_A);
  unsigned char* Bws    = (unsigned char*)(ws + WS_B);
  float4*        topE   = (float4*)(ws + WS_TOPE);
  unsigned*      counts = (unsigned*)(ws + WS_COUNTS);
  unsigned*      flags  = (unsigned*)(ws + WS_FLAGS);
  int*           idxf   = (int*)(ws + WS_IDX);
  int*           items  = (int*)(ws + WS_ITEMS);
  double*        cpart  = (double*)(ws + WS_CPART);

  prep_kernel<<<(NROWS + NCODES) / 4, 256, 0, stream>>>(z, cb, Aws, Bws, counts);
  gemm_p1_kernel<<<1024, 256, 0, stream>>>(Aws, Bws, topE);
  resolve_kernel<<<NROWS / 256, 256, 0, stream>>>((const uint4*)mk, topE, idxf, items, flags);
  groupscan_kernel<<<2048, 256, 0, stream>>>(z, cb, items, flags, idxf);
  outputs_kernel<<<NROWS / 4, 256, 0, stream>>>(z, cb, (const unsigned char*)mk, (const int*)mk,
                                                flags, idxf, out, counts, cpart);
  finalize_kernel<<<1, 256, 0, stream>>>(cpart, counts, out);
}

// Round 15
// 299.781 us; speedup vs baseline: 2.8721x; 1.1605x over previous
//
#include <hip/hip_runtime.h>

typedef __attribute__((ext_vector_type(4))) float f32x4_t;
typedef __attribute__((ext_vector_type(8))) short bf16x8_t;

#define NROWS 16384
#define NCODES 4096
#define DIM 512
#define DELTA 0.005f     // > worst-case |f64 referee - hi-only bf16 pass1| = 0.0040
#define MAXC 16          // explicit candidate cap per row (overflow -> group bit)

// ---------------- workspace byte offsets (~41.4 MB; harness provides >=45.6 MB, proven round 4) ----------------
#define WS_A      0u          // 128 tb x 8 st x 16KB (BK=64 stages) -> 16777216
#define WS_B      16777216u   //  32 ct x 8 st x 16KB -> 20971520
#define WS_TOPE   20971520u   // [row 16384][hg 64] float4 -> 37748736
#define WS_COUNTS 37748736u   // 4096 u32 -> 37765120
#define WS_FLAGS  37765120u   // [0]=mask-layout [1]=item_cnt -> +64
#define WS_IDX    37765184u   // 16384 i32 -> 37830720
#define WS_ITEMS  37830720u   // 16384 x 20 i32 {row,cnt,maskLo,maskHi,cid[16]} -> 39141440
#define WS_CPART  39206976u   // 4096 f64 -> 39239744
#define WS_GPART  39239744u   // 16384 x 8 double2 -> 41336896

// output element offsets (flat f32)
#define OUT_ZQ      0
#define OUT_ZQST    8388608
#define OUT_IDX     16777216
#define OUT_VQ      16793600
#define OUT_COMMIT  16793601
#define OUT_PERP    16793602

__device__ __forceinline__ unsigned short f2bf(float x) {
  unsigned u = __builtin_bit_cast(unsigned, x);
  unsigned r = (u + 0x7FFFu + ((u >> 16) & 1u)) >> 16;  // RNE
  return (unsigned short)r;
}
__device__ __forceinline__ unsigned hz(unsigned x) {
  return (x - 0x01010101u) & ~x & 0x80808080u;  // any zero byte
}
// BK=64 stage layout: row r in [0,128) is 128B (8 x 16B units); XOR keeps ds_read banks 2-way (free)
__device__ __forceinline__ unsigned swz64(int r, int u) {
  return (unsigned)(r * 128 + ((u ^ (r & 7)) << 4));
}

// ---------------- prep: norms + bf16-hi convert into swizzled 16KB stage-chunks + zero counts/flags ----------------
__global__ void prep_kernel(const float* __restrict__ z, const float* __restrict__ cb,
                            unsigned char* __restrict__ Aws, unsigned char* __restrict__ Bws,
                            unsigned* __restrict__ counts) {
  if (blockIdx.x < 17) {
    int zi = blockIdx.x * 256 + threadIdx.x;
    if (zi < 4100) counts[zi] = 0;  // counts[4096] + flags[4] contiguous
  }
  const int wv = threadIdx.x >> 6, lane = threadIdx.x & 63;
  const int row = blockIdx.x * 4 + wv;
  if (row >= NROWS + NCODES) return;
  const bool isA = row < NROWS;
  const int lrow = isA ? row : row - NROWS;
  const float* src = (isA ? z : cb) + (size_t)lrow * DIM;
  f32x4_t a = *(const f32x4_t*)(src + lane * 8);
  f32x4_t b = *(const f32x4_t*)(src + lane * 8 + 4);
  double s = 0.0;
#pragma unroll
  for (int e = 0; e < 4; ++e) s += (double)a[e] * a[e] + (double)b[e] * b[e];
#pragma unroll
  for (int off = 1; off < 64; off <<= 1) s += __shfl_xor(s, off);
  const float inv = (float)(1.0 / fmax(sqrt(s), 1e-8));
  union { unsigned short u[8]; uint4 v; } H;
#pragma unroll
  for (int e = 0; e < 4; ++e) {
    H.u[e] = f2bf(a[e] * inv);
    H.u[4 + e] = f2bf(b[e] * inv);
  }
  const int tb = lrow >> 7, rr = lrow & 127;
  const int st = lane >> 3, u = lane & 7;  // stage = 64 cols, unit = 8 cols
  unsigned char* chunk = (isA ? Aws : Bws) + ((size_t)tb * 8 + st) * 16384;
  *(uint4*)(chunk + swz64(rr, u)) = H.v;
}

// ---------------- pass-1 GEMM: BK=64 single-buffer + in-register cross-lane top-2 epilogue ----------------
__global__ __launch_bounds__(256, 4) void gemm_p1_kernel(
    const unsigned char* __restrict__ Aws, const unsigned char* __restrict__ Bws,
    float4* __restrict__ topE) {
  __align__(16) __shared__ unsigned char smem[32768];  // staging only (A 16K | B 16K)

  const int tid = threadIdx.x;
  const int bid = blockIdx.x;
  const int xcd = bid & 7, q = bid >> 3;
  const int rb = xcd * 16 + (q >> 3), cg = q & 7;  // XCD-aware: 8 cg-blocks of one rb share an XCD L2
  const int wave = tid >> 6, lane = tid & 63;
  const int wr = wave >> 1, wc = wave & 1;
  const int kg = lane >> 4, lr = lane & 15;

  const unsigned char* Ach = Aws + (size_t)rb * 8 * 16384;

  auto issue_stage = [&](const unsigned char* Asrc, const unsigned char* Bsrc) {
#pragma unroll
    for (int i = 0; i < 8; ++i) {
      const int j = wave * 8 + i;  // 32 x 1KB units: A 0-15 -> lds 0-16K, B 16-31 -> lds 16-32K
      const unsigned char* sp = (j < 16) ? (Asrc + (size_t)j * 1024 + lane * 16)
                                         : (Bsrc + (size_t)(j - 16) * 1024 + lane * 16);
      __builtin_amdgcn_global_load_lds(
          (const __attribute__((address_space(1))) void*)sp,
          (__attribute__((address_space(3))) void*)(smem + j * 1024), 16, 0, 0);
    }
  };

  for (int ct = 0; ct < 4; ++ct) {
    const int ctile = cg * 4 + ct;
    const int code0 = ctile * 128;
    const unsigned char* Bch = Bws + (size_t)ctile * 8 * 16384;

    f32x4_t acc[4][4];
#pragma unroll
    for (int m = 0; m < 4; ++m)
#pragma unroll
      for (int n = 0; n < 4; ++n) acc[m][n] = (f32x4_t){0.f, 0.f, 0.f, 0.f};

    for (int st = 0; st < 8; ++st) {
      if (!(st == 0 && ct > 0))  // ct>0 stage-0 was pre-issued before previous epilogue
        issue_stage(Ach + (size_t)st * 16384, Bch + (size_t)st * 16384);
      __syncthreads();  // compiler drains vmcnt before barrier (m97 pattern)

#pragma unroll
      for (int kk = 0; kk < 2; ++kk) {  // two 32-col halves; frags scoped to stay <=128 VGPR
        bf16x8_t ah[4], bh[4];
        const int u = kk * 4 + kg;
#pragma unroll
        for (int m = 0; m < 4; ++m) {
          const int r = wr * 64 + m * 16 + lr;
          ah[m] = *(const bf16x8_t*)(smem + swz64(r, u));
        }
#pragma unroll
        for (int n = 0; n < 4; ++n) {
          const int r = wc * 64 + n * 16 + lr;
          bh[n] = *(const bf16x8_t*)(smem + 16384 + swz64(r, u));
        }
#pragma unroll
        for (int m = 0; m < 4; ++m)
#pragma unroll
          for (int n = 0; n < 4; ++n)
            acc[m][n] = __builtin_amdgcn_mfma_f32_16x16x32_bf16(ah[m], bh[n], acc[m][n], 0, 0, 0);
      }
      __syncthreads();  // reads done before next stage overwrites
    }

    // pre-issue next ct's first stage: its HBM/L2 latency hides under the butterfly below
    if (ct < 3)
      issue_stage(Ach, Bws + (size_t)(ctile + 1) * 8 * 16384);

    // epilogue: exact top-2 per (row, 64-code half) fully in-register (no LDS, no barriers)
#pragma unroll
    for (int m = 0; m < 4; ++m) {
#pragma unroll
      for (int j = 0; j < 4; ++j) {
        float v1 = -3e38f, v2 = -3e38f; int i1 = 0, i2 = 0;
#pragma unroll
        for (int n = 0; n < 4; ++n) {  // ascending code order; strict > keeps smallest index on ties
          float v = acc[m][n][j];
          int gc = code0 + wc * 64 + n * 16 + lr;
          if (v > v1) { v2 = v1; i2 = i1; v1 = v; i1 = gc; }
          else if (v > v2) { v2 = v; i2 = gc; }
        }
#pragma unroll
        for (int mask = 1; mask <= 8; mask <<= 1) {  // butterfly over lr: merge sorted-2 lists
          float ov1 = __shfl_xor(v1, mask); int oi1 = __shfl_xor(i1, mask);
          float ov2 = __shfl_xor(v2, mask); int oi2 = __shfl_xor(i2, mask);
          bool of = (ov1 > v1) || (ov1 == v1 && oi1 < i1);
          float w1 = of ? ov1 : v1;  int k1 = of ? oi1 : i1;
          float lv = of ? v1 : ov1;  int li = of ? i1 : oi1;
          float sv = of ? ov2 : v2;  int si = of ? oi2 : i2;
          bool lw = (lv > sv) || (lv == sv && li < si);
          v1 = w1; i1 = k1;
          v2 = lw ? lv : sv; i2 = lw ? li : si;
        }
        if (lr == m * 4 + j) {  // one lane per (m,j): every lane writes exactly one float4
          const int row = rb * 128 + wr * 64 + m * 16 + kg * 4 + j;
          topE[(size_t)row * 64 + ctile * 2 + wc] =
              make_float4(v1, __builtin_bit_cast(float, i1), v2, __builtin_bit_cast(float, i2));
        }
      }
    }
  }
}

// ---------------- resolve: mask probe + classify rows into {direct, groupscan item} ----------------
__global__ void resolve_kernel(const uint4* __restrict__ mk, const float4* __restrict__ topE,
                               int* __restrict__ idxf, int* __restrict__ items,
                               unsigned* __restrict__ flags) {
  if (blockIdx.x == 0) {
    unsigned f = 0;
    for (int i = threadIdx.x; i < 1024; i += 256) {
      uint4 v = mk[i];
      f |= hz(v.x) | hz(v.y) | hz(v.z) | hz(v.w);
    }
    if (f) atomicOr(&flags[0], 1u);  // zero byte found -> int32 mask layout
  }
  const int row = blockIdx.x * 256 + threadIdx.x;
  if (row >= NROWS) return;
  const float4* e = topE + (size_t)row * 64;
  float V1 = -3e38f; int I1 = 0;
  for (int h = 0; h < 64; ++h) {  // hg ascending = code ascending; strict > = np smallest-index ties
    float4 qv = e[h];
    if (qv.x > V1) { V1 = qv.x; I1 = __builtin_bit_cast(int, qv.y); }
  }
  const float T = V1 - 2.0f * DELTA;
  unsigned long long smask = 0ull;  // suspect half-groups: their top-2 may hide a 3rd candidate
  int cnt = 0; int cid[MAXC];
  for (int h = 0; h < 64; ++h) {
    float4 qv = e[h];
    if (qv.x >= T) {
      if (cnt < MAXC) cid[cnt++] = __builtin_bit_cast(int, qv.y);
      else smask |= 1ull << h;           // overflow candidate -> scan its whole group
    }
    if (qv.z >= T) smask |= 1ull << h;   // group 2nd-best in window -> scan whole group
  }
  idxf[row] = I1;  // exact when cnt==1 && smask==0 (only one code can reach V1 within error bound)
  if (cnt >= 2 || smask != 0ull) {
    unsigned s = atomicAdd(&flags[1], 1u);
    if (s < NROWS) {
      int* o = items + (size_t)s * 20;
      o[0] = row; o[1] = cnt;
      o[2] = (int)(unsigned)(smask & 0xFFFFFFFFull);
      o[3] = (int)(unsigned)(smask >> 32);
#pragma unroll
      for (int c2 = 0; c2 < MAXC; ++c2) o[4 + c2] = (c2 < cnt) ? cid[c2] : 0;
    }
  }
}

// ---------------- f64 referee stage 1: (item, slot) work units; slot j scores codes j, j+8, ... ----------------
__global__ void groupscan_part(const float* __restrict__ z, const float* __restrict__ cb,
                               const int* __restrict__ items, const unsigned* __restrict__ flags,
                               double2* __restrict__ gpart) {
  const int lane = threadIdx.x & 63;
  const int gw = (blockIdx.x * 256 + threadIdx.x) >> 6;
  const int nwaves = gridDim.x * 4;
  unsigned n = flags[1];
  if (n > (unsigned)NROWS) n = NROWS;
  const unsigned tot = n * 8u;
  for (unsigned u = gw; u < tot; u += nwaves) {
    const unsigned it = u >> 3;
    const int slot = (int)(u & 7u);
    const int* en = items + (size_t)it * 20;
    const int row = en[0], cnt = en[1];
    const unsigned long long smask = ((unsigned long long)(unsigned)en[3] << 32) | (unsigned)en[2];
    const int total = cnt + 64 * __popcll(smask);
    double bs = -1e300; int bi = 1 << 30;
    if (slot < total) {
      const float* zr = z + (size_t)row * DIM + lane * 8;
      double zv[8];
#pragma unroll
      for (int j = 0; j < 8; ++j) zv[j] = (double)zr[j];
      auto code_at = [&](int w) -> int {
        if (w < cnt) return en[4 + w];
        const int qq = w - cnt;
        const int gsel = qq >> 6, off = qq & 63;
        unsigned long long m = smask;
        for (int i = 0; i < gsel; ++i) m &= m - 1;
        return (int)__builtin_ctzll(m) * 64 + off;
      };
      auto score2 = [&](int k0, int k1) {  // two codes with ILP; k1<0 -> single
        const float* c0 = cb + (size_t)k0 * DIM + lane * 8;
        const float* c1 = cb + (size_t)((k1 < 0) ? k0 : k1) * DIM + lane * 8;
        double d0 = 0, n0 = 0, d1 = 0, n1 = 0;
#pragma unroll
        for (int j = 0; j < 8; ++j) {
          double a = c0[j]; d0 += zv[j] * a; n0 += a * a;
          double b = c1[j]; d1 += zv[j] * b; n1 += b * b;
        }
#pragma unroll
        for (int off = 1; off < 64; off <<= 1) {
          d0 += __shfl_xor(d0, off); n0 += __shfl_xor(n0, off);
          d1 += __shfl_xor(d1, off); n1 += __shfl_xor(n1, off);
        }
        double s0 = d0 / sqrt(n0);
        if (s0 > bs || (s0 == bs && k0 < bi)) { bs = s0; bi = k0; }
        if (k1 >= 0) {
          double s1 = d1 / sqrt(n1);
          if (s1 > bs || (s1 == bs && k1 < bi)) { bs = s1; bi = k1; }
        }
      };
      int w = slot;
      while (w < total) {
        const int k0 = code_at(w); w += 8;
        const int k1 = (w < total) ? code_at(w) : -1; w += 8;
        score2(k0, k1);
      }
    }
    if (lane == 0) gpart[u] = make_double2(bs, (double)bi);
  }
}

// ---------------- f64 referee stage 2: merge 8 slot-bests per item ----------------
__global__ void groupscan_merge(const double2* __restrict__ gpart, const int* __restrict__ items,
                                const unsigned* __restrict__ flags, int* __restrict__ idxf) {
  unsigned n = flags[1];
  if (n > (unsigned)NROWS) n = NROWS;
  for (unsigned it = blockIdx.x * 256 + threadIdx.x; it < n; it += gridDim.x * 256) {
    double bs = -1e300; int bi = 1 << 30;
#pragma unroll
    for (int s2 = 0; s2 < 8; ++s2) {
      double2 e = gpart[(size_t)it * 8 + s2];
      const int k = (int)e.y;
      if (e.x > bs || (e.x == bs && k < bi)) { bs = e.x; bi = k; }
    }
    if (bi < NCODES) idxf[items[(size_t)it * 20]] = bi;
  }
}

// ---------------- gather + straight-through + partial losses ----------------
__global__ void outputs_kernel(const float* __restrict__ z, const float* __restrict__ cb,
                               const unsigned char* __restrict__ mask8, const int* __restrict__ mask32,
                               const unsigned* __restrict__ flags, const int* __restrict__ idxf,
                               float* __restrict__ out, unsigned* __restrict__ counts,
                               double* __restrict__ cpart) {
  __shared__ double wsum[4];
  const int wv = threadIdx.x >> 6, lane = threadIdx.x & 63;
  const int row = blockIdx.x * 4 + wv;
  int idx = idxf[row];
  idx = (idx < 0) ? 0 : ((idx > NCODES - 1) ? NCODES - 1 : idx);  // defensive clamp
  const int mi = flags[0] ? (mask32[row] != 0) : (mask8[row] != 0);
  const float mf = mi ? 1.0f : 0.0f;
  const float* zr = z + (size_t)row * DIM;
  const float* cr = cb + (size_t)idx * DIM;
  double cs = 0.0;
#pragma unroll
  for (int h = 0; h < 2; ++h) {
    const int j = h * 256 + lane * 4;
    f32x4_t c  = *(const f32x4_t*)(cr + j);
    f32x4_t ze = *(const f32x4_t*)(zr + j);
    f32x4_t zq, zs;
#pragma unroll
    for (int e = 0; e < 4; ++e) {
      float qv = c[e] * mf;
      float d = qv - ze[e];
      zq[e] = qv;
      zs[e] = ze[e] + d;
      cs += (double)(d * d) * mf;
    }
    *(f32x4_t*)(out + OUT_ZQ   + (size_t)row * DIM + j) = zq;
    *(f32x4_t*)(out + OUT_ZQST + (size_t)row * DIM + j) = zs;
  }
#pragma unroll
  for (int off = 32; off; off >>= 1) cs += __shfl_down(cs, off);
  if (lane == 0) {
    wsum[wv] = cs;
    out[OUT_IDX + row] = (float)idx;
    if (mi) atomicAdd(&counts[idx], 1u);
  }
  __syncthreads();
  if (threadIdx.x == 0) cpart[blockIdx.x] = wsum[0] + wsum[1] + wsum[2] + wsum[3];
}

// ---------------- scalars ----------------
__global__ void finalize_kernel(const double* __restrict__ cpart, const unsigned* __restrict__ counts,
                                float* __restrict__ out) {
  __shared__ double sd[256];
  const int t = threadIdx.x;
  double s = 0;
  for (int i = t; i < 4096; i += 256) s += cpart[i];
  sd[t] = s; __syncthreads();
  for (int off = 128; off; off >>= 1) { if (t < off) sd[t] += sd[t + off]; __syncthreads(); }
  const double commit_sum = sd[0];
  __syncthreads();
  double c = 0;
  for (int i = t; i < 4096; i += 256) c += (double)counts[i];
  sd[t] = c; __syncthreads();
  for (int off = 128; off; off >>= 1) { if (t < off) sd[t] += sd[t + off]; __syncthreads(); }
  const double totc = sd[0];
  __syncthreads();
  const double denom = totc + 1e-5;
  double ent = 0;
  for (int i = t; i < 4096; i += 256) {
    double p = (double)counts[i] / denom;
    ent -= p * log(p + 1e-5);
  }
  sd[t] = ent; __syncthreads();
  for (int off = 128; off; off >>= 1) { if (t < off) sd[t] += sd[t + off]; __syncthreads(); }
  if (t == 0) {
    const double valid = fmax(totc, 1.0);
    const double commitment = commit_sum / valid;
    out[OUT_VQ]     = (float)(0.25 * commitment);
    out[OUT_COMMIT] = (float)commitment;
    out[OUT_PERP]   = (float)exp(sd[0]);
  }
}

extern "C" void kernel_launch(void* const* d_in, const int* in_sizes, int n_in,
                              void* d_out, int out_size, void* d_ws, size_t ws_size,
                              hipStream_t stream) {
  const float* z  = (const float*)d_in[0];
  const void*  mk = d_in[1];
  const float* cb = (const float*)d_in[2];
  float* out = (float*)d_out;
  char* ws = (char*)d_ws;

  unsigned char* Aws    = (unsigned char*)(ws + WS_A);
  unsigned char* Bws    = (unsigned char*)(ws + WS_B);
  float4*        topE   = (float4*)(ws + WS_TOPE);
  unsigned*      counts = (unsigned*)(ws + WS_COUNTS);
  unsigned*      flags  = (unsigned*)(ws + WS_FLAGS);
  int*           idxf   = (int*)(ws + WS_IDX);
  int*           items  = (int*)(ws + WS_ITEMS);
  double*        cpart  = (double*)(ws + WS_CPART);
  double2*       gpart  = (double2*)(ws + WS_GPART);

  prep_kernel<<<(NROWS + NCODES) / 4, 256, 0, stream>>>(z, cb, Aws, Bws, counts);
  gemm_p1_kernel<<<1024, 256, 0, stream>>>(Aws, Bws, topE);
  resolve_kernel<<<NROWS / 256, 256, 0, stream>>>((const uint4*)mk, topE, idxf, items, flags);
  groupscan_part<<<2048, 256, 0, stream>>>(z, cb, items, flags, gpart);
  groupscan_merge<<<64, 256, 0, stream>>>(gpart, items, flags, idxf);
  outputs_kernel<<<NROWS / 4, 256, 0, stream>>>(z, cb, (const unsigned char*)mk, (const int*)mk,
                                                flags, idxf, out, counts, cpart);
  finalize_kernel<<<1, 256, 0, stream>>>(cpart, counts, out);
}